// Round 1
// baseline (852.697 us; speedup 1.0000x reference)
//
#include <hip/hip_runtime.h>
#include <hip/hip_bf16.h>

#define KN 16384
#define KD 1024

typedef __attribute__((ext_vector_type(8))) short bf16x8;   // 8 bf16 (4 VGPRs)
typedef __attribute__((ext_vector_type(4))) float f32x4;    // MFMA 16x16 accumulator

__device__ __forceinline__ void load_lds16(const void* g, void* l) {
  // async global->LDS, 16B/lane; LDS dest is wave-uniform base + lane*16
  __builtin_amdgcn_global_load_lds(
      (const __attribute__((address_space(1))) unsigned int*)g,
      (__attribute__((address_space(3))) unsigned int*)l, 16, 0, 0);
}

struct bf4 { __hip_bfloat16 a, b, c, d; };  // 8-byte packed store

// ---------------- row L2-normalize, fp32 -> bf16 ----------------
__global__ __launch_bounds__(256) void k_normalize(const float* __restrict__ x,
                                                   __hip_bfloat16* __restrict__ xn) {
  const int row = blockIdx.x;
  const int tid = threadIdx.x;
  const float4 v = ((const float4*)(x + (size_t)row * KD))[tid];
  float ss = v.x * v.x + v.y * v.y + v.z * v.z + v.w * v.w;
#pragma unroll
  for (int off = 32; off > 0; off >>= 1) ss += __shfl_down(ss, off);
  __shared__ float ws[4];
  if ((tid & 63) == 0) ws[tid >> 6] = ss;
  __syncthreads();
  const float total = ws[0] + ws[1] + ws[2] + ws[3];
  const float scale = 1.0f / fmaxf(sqrtf(total), 1e-8f);  // F.normalize eps=1e-8
  bf4 o;
  o.a = __float2bfloat16(v.x * scale);
  o.b = __float2bfloat16(v.y * scale);
  o.c = __float2bfloat16(v.z * scale);
  o.d = __float2bfloat16(v.w * scale);
  ((bf4*)(xn + (size_t)row * KD))[tid] = o;
}

// ---------------- fused NT-GEMM (xn . xn^T) + per-row argmax ----------------
// 128x128 tile/block, 4 waves in 2x2, 64x64 per wave, 16x16x32 bf16 MFMA.
// Epilogue: argmax over the 128-col tile, merged globally via packed u64 atomicMax.
__global__ __launch_bounds__(256) void k_nn_argmax(const __hip_bfloat16* __restrict__ xn,
                                                   unsigned long long* __restrict__ best) {
  __shared__ __hip_bfloat16 As[128 * 32];
  __shared__ __hip_bfloat16 Bs[128 * 32];
  const int tid  = threadIdx.x;
  const int bx   = blockIdx.x;          // col block
  const int by   = blockIdx.y;          // row block
  const int lane = tid & 63;
  const int wave = tid >> 6;
  const int wm   = wave >> 1;           // wave row (0..1)
  const int wn   = wave & 1;            // wave col (0..1)
  const int quad = lane >> 4;
  const int l15  = lane & 15;

  f32x4 acc[4][4];
#pragma unroll
  for (int i = 0; i < 4; i++)
#pragma unroll
    for (int j = 0; j < 4; j++) acc[i][j] = (f32x4){0.f, 0.f, 0.f, 0.f};

  // staging: 128x32 bf16 tile = 8KB; 256 lanes x 16B = 4KB/call -> 2 calls/tile
  const int arow = (by << 7) + (tid >> 2);
  const int brow = (bx << 7) + (tid >> 2);
  const int kg   = (tid & 3) << 3;      // bf16 element offset within the 32-wide k slab

  for (int k0 = 0; k0 < KD; k0 += 32) {
    load_lds16(xn + (size_t)arow * KD + k0 + kg,        &As[tid * 8]);
    load_lds16(xn + (size_t)(arow + 64) * KD + k0 + kg, &As[(256 + tid) * 8]);
    load_lds16(xn + (size_t)brow * KD + k0 + kg,        &Bs[tid * 8]);
    load_lds16(xn + (size_t)(brow + 64) * KD + k0 + kg, &Bs[(256 + tid) * 8]);
    __syncthreads();  // drains vmcnt before LDS reads

    bf16x8 a[4], b[4];
#pragma unroll
    for (int i = 0; i < 4; i++)
      a[i] = *(const bf16x8*)&As[(wm * 64 + i * 16 + l15) * 32 + quad * 8];
#pragma unroll
    for (int j = 0; j < 4; j++)
      b[j] = *(const bf16x8*)&Bs[(wn * 64 + j * 16 + l15) * 32 + quad * 8];
#pragma unroll
    for (int i = 0; i < 4; i++)
#pragma unroll
      for (int j = 0; j < 4; j++)
        acc[i][j] = __builtin_amdgcn_mfma_f32_16x16x32_bf16(a[i], b[j], acc[i][j], 0, 0, 0);
    __syncthreads();
  }

  // Epilogue: C/D layout (16x16x32): col = lane&15, row = quad*4 + reg.
  // For each of the wave's 64 rows: max over its 64 cols, then atomicMax-merge.
#pragma unroll
  for (int i = 0; i < 4; i++) {
#pragma unroll
    for (int r = 0; r < 4; r++) {
      const int grow = (by << 7) + wm * 64 + i * 16 + quad * 4 + r;
      float v = -3.0f;
      int   c = 0;
#pragma unroll
      for (int j = 0; j < 4; j++) {
        const int gcol = (bx << 7) + wn * 64 + j * 16 + l15;
        float val = acc[i][j][r];
        if (gcol == grow) val = -3.0f;  // mask self-similarity (ref sets -1.0)
        if (val > v) { v = val; c = gcol; }
      }
      // argmax across the 16 lanes of this quad (they hold the 16 cols of a row)
#pragma unroll
      for (int off = 1; off < 16; off <<= 1) {
        const float ov = __shfl_xor(v, off);
        const int   oc = __shfl_xor(c, off);
        if (ov > v) { v = ov; c = oc; }
      }
      if (l15 == 0) {
        unsigned u = __float_as_uint(v);
        u = (u & 0x80000000u) ? ~u : (u | 0x80000000u);  // order-preserving encode
        const unsigned long long p = ((unsigned long long)u << 32) | (unsigned)c;
        atomicMax(best + grow, p);
      }
    }
  }
}

// ---------------- distance to NN + -log ----------------
__global__ __launch_bounds__(256) void k_dist(const float* __restrict__ x,
                                              const unsigned long long* __restrict__ best,
                                              float* __restrict__ rowlog) {
  const int row = blockIdx.x;
  const int nb  = (int)(best[row] & 0xffffffffu);
  const int tid = threadIdx.x;
  const float4 a = ((const float4*)(x + (size_t)row * KD))[tid];
  const float4 b = ((const float4*)(x + (size_t)nb * KD))[tid];
  const float dx = a.x - b.x + 1e-6f;   // torch PairwiseDistance eps on the diff
  const float dy = a.y - b.y + 1e-6f;
  const float dz = a.z - b.z + 1e-6f;
  const float dw = a.w - b.w + 1e-6f;
  float ss = dx * dx + dy * dy + dz * dz + dw * dw;
#pragma unroll
  for (int off = 32; off > 0; off >>= 1) ss += __shfl_down(ss, off);
  __shared__ float ws[4];
  if ((tid & 63) == 0) ws[tid >> 6] = ss;
  __syncthreads();
  if (tid == 0) {
    const float total = ws[0] + ws[1] + ws[2] + ws[3];
    rowlog[row] = -logf(sqrtf(total));
  }
}

// ---------------- final mean ----------------
__global__ __launch_bounds__(256) void k_final(const float* __restrict__ rowlog,
                                               float* __restrict__ out) {
  const int tid = threadIdx.x;
  float s = 0.f;
  for (int i = tid; i < KN; i += 256) s += rowlog[i];
#pragma unroll
  for (int off = 32; off > 0; off >>= 1) s += __shfl_down(s, off);
  __shared__ float ws[4];
  if ((tid & 63) == 0) ws[tid >> 6] = s;
  __syncthreads();
  if (tid == 0) out[0] = (ws[0] + ws[1] + ws[2] + ws[3]) / (float)KN;
}

extern "C" void kernel_launch(void* const* d_in, const int* in_sizes, int n_in,
                              void* d_out, int out_size, void* d_ws, size_t ws_size,
                              hipStream_t stream) {
  const float* x = (const float*)d_in[0];
  float* out = (float*)d_out;

  char* ws = (char*)d_ws;
  __hip_bfloat16* xn = (__hip_bfloat16*)ws;                                   // 32 MB
  unsigned long long* best = (unsigned long long*)(ws + (size_t)KN * KD * 2); // 128 KB
  float* rowlog = (float*)(ws + (size_t)KN * KD * 2 + (size_t)KN * 8);        // 64 KB

  k_normalize<<<KN, 256, 0, stream>>>(x, xn);
  hipMemsetAsync(best, 0, (size_t)KN * sizeof(unsigned long long), stream);   // enc(any dot) > 0
  dim3 grid(KN / 128, KN / 128);
  k_nn_argmax<<<grid, 256, 0, stream>>>(xn, best);
  k_dist<<<KN, 256, 0, stream>>>(x, best, rowlog);
  k_final<<<1, 256, 0, stream>>>(rowlog, out);
}

// Round 2
// 610.788 us; speedup vs baseline: 1.3961x; 1.3961x over previous
//
#include <hip/hip_runtime.h>
#include <hip/hip_bf16.h>

#define KN 16384
#define KD 1024
#define NB (KN / 128)   // 128 tile-blocks per dimension

typedef __attribute__((ext_vector_type(8))) short bf16x8;   // 8 bf16 (4 VGPRs)
typedef __attribute__((ext_vector_type(4))) float f32x4;    // MFMA 16x16 accumulator

__device__ __forceinline__ void load_lds16(const void* g, void* l) {
  // async global->LDS, 16B/lane; LDS dest is wave-uniform base + lane*16
  __builtin_amdgcn_global_load_lds(
      (const __attribute__((address_space(1))) unsigned int*)g,
      (__attribute__((address_space(3))) unsigned int*)l, 16, 0, 0);
}

__device__ __forceinline__ unsigned long long pack_max(float v, int idx) {
  unsigned u = __float_as_uint(v);
  u = (u & 0x80000000u) ? ~u : (u | 0x80000000u);  // order-preserving encode
  return ((unsigned long long)u << 32) | (unsigned)idx;
}

struct bf4 { __hip_bfloat16 a, b, c, d; };  // 8-byte packed store

// ---------------- row L2-normalize, fp32 -> bf16 ----------------
__global__ __launch_bounds__(256) void k_normalize(const float* __restrict__ x,
                                                   __hip_bfloat16* __restrict__ xn) {
  const int row = blockIdx.x;
  const int tid = threadIdx.x;
  const float4 v = ((const float4*)(x + (size_t)row * KD))[tid];
  float ss = v.x * v.x + v.y * v.y + v.z * v.z + v.w * v.w;
#pragma unroll
  for (int off = 32; off > 0; off >>= 1) ss += __shfl_down(ss, off);
  __shared__ float ws[4];
  if ((tid & 63) == 0) ws[tid >> 6] = ss;
  __syncthreads();
  const float total = ws[0] + ws[1] + ws[2] + ws[3];
  const float scale = 1.0f / fmaxf(sqrtf(total), 1e-8f);  // F.normalize eps=1e-8
  bf4 o;
  o.a = __float2bfloat16(v.x * scale);
  o.b = __float2bfloat16(v.y * scale);
  o.c = __float2bfloat16(v.z * scale);
  o.d = __float2bfloat16(v.w * scale);
  ((bf4*)(xn + (size_t)row * KD))[tid] = o;
}

// ---------------- fused symmetric NT-GEMM (xn . xn^T) + two-sided argmax ----
// Only upper-triangular 128x128 tile pairs are computed (circulant mapping:
// bx = (by + d) % NB, d in [0,64]; d==64 processed only for by<64 to avoid
// the duplicate of pair {by, by+64}). Off-diagonal blocks feed BOTH the row
// argmax and (via symmetry) the column argmax -> half the MFMA work.
__global__ __launch_bounds__(256) void k_nn_argmax(const __hip_bfloat16* __restrict__ xn,
                                                   unsigned long long* __restrict__ best) {
  const int d  = blockIdx.x;            // tile distance 0..64
  const int by = blockIdx.y;            // row tile
  if (d == NB / 2 && by >= NB / 2) return;  // {by, by+64} pair counted once
  const int bx = (by + d) & (NB - 1);   // col tile

  __shared__ __hip_bfloat16 As[128 * 32];
  __shared__ __hip_bfloat16 Bs[128 * 32];
  const int tid  = threadIdx.x;
  const int lane = tid & 63;
  const int wave = tid >> 6;
  const int wm   = wave >> 1;           // wave row (0..1)
  const int wn   = wave & 1;            // wave col (0..1)
  const int quad = lane >> 4;
  const int l15  = lane & 15;

  f32x4 acc[4][4];
#pragma unroll
  for (int i = 0; i < 4; i++)
#pragma unroll
    for (int j = 0; j < 4; j++) acc[i][j] = (f32x4){0.f, 0.f, 0.f, 0.f};

  // staging: 128x32 bf16 tile = 8KB; 256 lanes x 16B = 4KB/call -> 2 calls/tile
  const int arow = (by << 7) + (tid >> 2);
  const int brow = (bx << 7) + (tid >> 2);
  const int kg   = (tid & 3) << 3;      // bf16 element offset within the 32-wide k slab

  for (int k0 = 0; k0 < KD; k0 += 32) {
    load_lds16(xn + (size_t)arow * KD + k0 + kg,        &As[tid * 8]);
    load_lds16(xn + (size_t)(arow + 64) * KD + k0 + kg, &As[(256 + tid) * 8]);
    load_lds16(xn + (size_t)brow * KD + k0 + kg,        &Bs[tid * 8]);
    load_lds16(xn + (size_t)(brow + 64) * KD + k0 + kg, &Bs[(256 + tid) * 8]);
    __syncthreads();  // drains vmcnt before LDS reads

    bf16x8 a[4], b[4];
#pragma unroll
    for (int i = 0; i < 4; i++)
      a[i] = *(const bf16x8*)&As[(wm * 64 + i * 16 + l15) * 32 + quad * 8];
#pragma unroll
    for (int j = 0; j < 4; j++)
      b[j] = *(const bf16x8*)&Bs[(wn * 64 + j * 16 + l15) * 32 + quad * 8];
#pragma unroll
    for (int i = 0; i < 4; i++)
#pragma unroll
      for (int j = 0; j < 4; j++)
        acc[i][j] = __builtin_amdgcn_mfma_f32_16x16x32_bf16(a[i], b[j], acc[i][j], 0, 0, 0);
    __syncthreads();
  }

  // Epilogue. C/D layout (16x16x32): col = lane&15, row = quad*4 + reg.
  // Row argmax: reduce over the 4 j-tiles locally, then across the 16 lanes
  // holding the row's 16 cols. Col argmax (symmetry, d>0 only): accumulate
  // per-lane over i,r (16 rows of the wave's strip), then reduce across quads.
  float colv[4];
  int   colr[4];
#pragma unroll
  for (int j = 0; j < 4; j++) { colv[j] = -3.0f; colr[j] = 0; }

#pragma unroll
  for (int i = 0; i < 4; i++) {
#pragma unroll
    for (int r = 0; r < 4; r++) {
      const int grow = (by << 7) + wm * 64 + i * 16 + quad * 4 + r;
      float v = -3.0f;
      int   c = 0;
#pragma unroll
      for (int j = 0; j < 4; j++) {
        const int gcol = (bx << 7) + wn * 64 + j * 16 + l15;
        float val = acc[i][j][r];
        if (gcol == grow) val = -3.0f;  // mask self-similarity
        if (val > v) { v = val; c = gcol; }
        if (val > colv[j]) { colv[j] = val; colr[j] = grow; }
      }
      // argmax across the 16 lanes of this quad (the row's 16 cols per tile)
#pragma unroll
      for (int off = 1; off < 16; off <<= 1) {
        const float ov = __shfl_xor(v, off);
        const int   oc = __shfl_xor(c, off);
        if (ov > v) { v = ov; c = oc; }
      }
      if (l15 == 0) atomicMax(best + grow, pack_max(v, c));
    }
  }

  if (d != 0) {  // diagonal block: col update is redundant with row update
#pragma unroll
    for (int j = 0; j < 4; j++) {
      float v = colv[j];
      int   r = colr[j];
      // reduce across the 4 quads (lanes sharing l15 -> same column)
#pragma unroll
      for (int off = 16; off < 64; off <<= 1) {
        const float ov = __shfl_xor(v, off);
        const int   orr = __shfl_xor(r, off);
        if (ov > v) { v = ov; r = orr; }
      }
      if (quad == 0) {
        const int gcol = (bx << 7) + wn * 64 + j * 16 + l15;
        atomicMax(best + gcol, pack_max(v, r));
      }
    }
  }
}

// ---------------- distance to NN + -log ----------------
__global__ __launch_bounds__(256) void k_dist(const float* __restrict__ x,
                                              const unsigned long long* __restrict__ best,
                                              float* __restrict__ rowlog) {
  const int row = blockIdx.x;
  const int nb  = (int)(best[row] & 0xffffffffu);
  const int tid = threadIdx.x;
  const float4 a = ((const float4*)(x + (size_t)row * KD))[tid];
  const float4 b = ((const float4*)(x + (size_t)nb * KD))[tid];
  const float dx = a.x - b.x + 1e-6f;   // torch PairwiseDistance eps on the diff
  const float dy = a.y - b.y + 1e-6f;
  const float dz = a.z - b.z + 1e-6f;
  const float dw = a.w - b.w + 1e-6f;
  float ss = dx * dx + dy * dy + dz * dz + dw * dw;
#pragma unroll
  for (int off = 32; off > 0; off >>= 1) ss += __shfl_down(ss, off);
  __shared__ float ws[4];
  if ((tid & 63) == 0) ws[tid >> 6] = ss;
  __syncthreads();
  if (tid == 0) {
    const float total = ws[0] + ws[1] + ws[2] + ws[3];
    rowlog[row] = -logf(sqrtf(total));
  }
}

// ---------------- final mean ----------------
__global__ __launch_bounds__(256) void k_final(const float* __restrict__ rowlog,
                                               float* __restrict__ out) {
  const int tid = threadIdx.x;
  float s = 0.f;
  for (int i = tid; i < KN; i += 256) s += rowlog[i];
#pragma unroll
  for (int off = 32; off > 0; off >>= 1) s += __shfl_down(s, off);
  __shared__ float ws[4];
  if ((tid & 63) == 0) ws[tid >> 6] = s;
  __syncthreads();
  if (tid == 0) out[0] = (ws[0] + ws[1] + ws[2] + ws[3]) / (float)KN;
}

extern "C" void kernel_launch(void* const* d_in, const int* in_sizes, int n_in,
                              void* d_out, int out_size, void* d_ws, size_t ws_size,
                              hipStream_t stream) {
  const float* x = (const float*)d_in[0];
  float* out = (float*)d_out;

  char* ws = (char*)d_ws;
  __hip_bfloat16* xn = (__hip_bfloat16*)ws;                                   // 32 MB
  unsigned long long* best = (unsigned long long*)(ws + (size_t)KN * KD * 2); // 128 KB
  float* rowlog = (float*)(ws + (size_t)KN * KD * 2 + (size_t)KN * 8);        // 64 KB

  k_normalize<<<KN, 256, 0, stream>>>(x, xn);
  hipMemsetAsync(best, 0, (size_t)KN * sizeof(unsigned long long), stream);   // enc(any dot) > 0
  dim3 grid(NB / 2 + 1, NB);            // circulant upper-triangle cover
  k_nn_argmax<<<grid, 256, 0, stream>>>(xn, best);
  k_dist<<<KN, 256, 0, stream>>>(x, best, rowlog);
  k_final<<<1, 256, 0, stream>>>(rowlog, out);
}

// Round 3
// 461.394 us; speedup vs baseline: 1.8481x; 1.3238x over previous
//
#include <hip/hip_runtime.h>
#include <hip/hip_bf16.h>

#define KN 16384
#define KD 1024
#define NB (KN / 128)   // 128 tile-blocks per dimension

typedef __attribute__((ext_vector_type(8))) short bf16x8;   // 8 bf16 (4 VGPRs)
typedef __attribute__((ext_vector_type(4))) float f32x4;    // MFMA 16x16 accumulator

__device__ __forceinline__ void load_lds16(const void* g, void* l) {
  // async global->LDS, 16B/lane; LDS dest is wave-uniform base + lane*16
  __builtin_amdgcn_global_load_lds(
      (const __attribute__((address_space(1))) unsigned int*)g,
      (__attribute__((address_space(3))) unsigned int*)l, 16, 0, 0);
}

__device__ __forceinline__ unsigned long long pack_max(float v, int idx) {
  unsigned u = __float_as_uint(v);
  u = (u & 0x80000000u) ? ~u : (u | 0x80000000u);  // order-preserving encode
  return ((unsigned long long)u << 32) | (unsigned)idx;
}

struct bf4 { __hip_bfloat16 a, b, c, d; };  // 8-byte packed store

// ---------------- row L2-normalize, fp32 -> bf16 (+ best[] init) ----------------
__global__ __launch_bounds__(256) void k_normalize(const float* __restrict__ x,
                                                   __hip_bfloat16* __restrict__ xn,
                                                   unsigned long long* __restrict__ best) {
  const int row = blockIdx.x;
  const int tid = threadIdx.x;
  if (tid == 0) best[row] = 0ull;  // enc(any dot >= -1) > 0, so 0 is identity
  const float4 v = ((const float4*)(x + (size_t)row * KD))[tid];
  float ss = v.x * v.x + v.y * v.y + v.z * v.z + v.w * v.w;
#pragma unroll
  for (int off = 32; off > 0; off >>= 1) ss += __shfl_down(ss, off);
  __shared__ float ws[4];
  if ((tid & 63) == 0) ws[tid >> 6] = ss;
  __syncthreads();
  const float total = ws[0] + ws[1] + ws[2] + ws[3];
  const float scale = 1.0f / fmaxf(sqrtf(total), 1e-8f);  // F.normalize eps=1e-8
  bf4 o;
  o.a = __float2bfloat16(v.x * scale);
  o.b = __float2bfloat16(v.y * scale);
  o.c = __float2bfloat16(v.z * scale);
  o.d = __float2bfloat16(v.w * scale);
  ((bf4*)(xn + (size_t)row * KD))[tid] = o;
}

// ---------------- fused symmetric NT-GEMM (xn . xn^T) + two-sided argmax ----
// Circulant upper-triangle cover: bx = (by + d) % NB, d in [0,64]; d==64 only
// for by<64. Off-diagonal blocks feed BOTH row argmax and (symmetry) col argmax.
// __launch_bounds__(256,3): 3 blocks/CU -> unified VGPR+AGPR cap 170. The
// epilogue is two passes over acc (row-major then col-major) so no extra
// per-lane arrays stay live and VGPR stays at the R1 level.
__global__ __launch_bounds__(256, 3) void k_nn_argmax(const __hip_bfloat16* __restrict__ xn,
                                                      unsigned long long* __restrict__ best) {
  const int d  = blockIdx.x;            // tile distance 0..64
  const int by = blockIdx.y;            // row tile
  if (d == NB / 2 && by >= NB / 2) return;  // {by, by+64} pair counted once
  const int bx = (by + d) & (NB - 1);   // col tile

  __shared__ __hip_bfloat16 As[128 * 32];
  __shared__ __hip_bfloat16 Bs[128 * 32];
  const int tid  = threadIdx.x;
  const int lane = tid & 63;
  const int wave = tid >> 6;
  const int wm   = wave >> 1;           // wave row (0..1)
  const int wn   = wave & 1;            // wave col (0..1)
  const int quad = lane >> 4;
  const int l15  = lane & 15;

  f32x4 acc[4][4];
#pragma unroll
  for (int i = 0; i < 4; i++)
#pragma unroll
    for (int j = 0; j < 4; j++) acc[i][j] = (f32x4){0.f, 0.f, 0.f, 0.f};

  // staging: 128x32 bf16 tile = 8KB; 256 lanes x 16B = 4KB/call -> 2 calls/tile
  const int arow = (by << 7) + (tid >> 2);
  const int brow = (bx << 7) + (tid >> 2);
  const int kg   = (tid & 3) << 3;      // bf16 element offset within the 32-wide k slab

  for (int k0 = 0; k0 < KD; k0 += 32) {
    load_lds16(xn + (size_t)arow * KD + k0 + kg,        &As[tid * 8]);
    load_lds16(xn + (size_t)(arow + 64) * KD + k0 + kg, &As[(256 + tid) * 8]);
    load_lds16(xn + (size_t)brow * KD + k0 + kg,        &Bs[tid * 8]);
    load_lds16(xn + (size_t)(brow + 64) * KD + k0 + kg, &Bs[(256 + tid) * 8]);
    __syncthreads();  // drains vmcnt before LDS reads

    bf16x8 a[4], b[4];
#pragma unroll
    for (int i = 0; i < 4; i++)
      a[i] = *(const bf16x8*)&As[(wm * 64 + i * 16 + l15) * 32 + quad * 8];
#pragma unroll
    for (int j = 0; j < 4; j++)
      b[j] = *(const bf16x8*)&Bs[(wn * 64 + j * 16 + l15) * 32 + quad * 8];
#pragma unroll
    for (int i = 0; i < 4; i++)
#pragma unroll
      for (int j = 0; j < 4; j++)
        acc[i][j] = __builtin_amdgcn_mfma_f32_16x16x32_bf16(a[i], b[j], acc[i][j], 0, 0, 0);
    __syncthreads();
  }

  // ---- Epilogue pass 1: row argmax (C/D layout: col = lane&15, row = quad*4+reg)
#pragma unroll
  for (int i = 0; i < 4; i++) {
#pragma unroll
    for (int r = 0; r < 4; r++) {
      const int grow = (by << 7) + wm * 64 + i * 16 + quad * 4 + r;
      float v = -3.0f;
      int   c = 0;
#pragma unroll
      for (int j = 0; j < 4; j++) {
        const int gcol = (bx << 7) + wn * 64 + j * 16 + l15;
        float val = acc[i][j][r];
        if (gcol == grow) val = -3.0f;  // mask self-similarity
        if (val > v) { v = val; c = gcol; }
      }
#pragma unroll
      for (int off = 1; off < 16; off <<= 1) {
        const float ov = __shfl_xor(v, off);
        const int   oc = __shfl_xor(c, off);
        if (ov > v) { v = ov; c = oc; }
      }
      if (l15 == 0) atomicMax(best + grow, pack_max(v, c));
    }
  }

  // ---- Epilogue pass 2: col argmax via symmetry (off-diagonal blocks only)
  if (d != 0) {
#pragma unroll
    for (int j = 0; j < 4; j++) {
      const int gcol = (bx << 7) + wn * 64 + j * 16 + l15;
      float v = -3.0f;
      int   rb = 0;
#pragma unroll
      for (int i = 0; i < 4; i++) {
#pragma unroll
        for (int r = 0; r < 4; r++) {
          const int grow = (by << 7) + wm * 64 + i * 16 + quad * 4 + r;
          float val = acc[i][j][r];
          if (gcol == grow) val = -3.0f;
          if (val > v) { v = val; rb = grow; }
        }
      }
      // reduce across the 4 quads (lanes sharing l15 hold the same column)
#pragma unroll
      for (int off = 16; off < 64; off <<= 1) {
        const float ov = __shfl_xor(v, off);
        const int   orr = __shfl_xor(rb, off);
        if (ov > v) { v = ov; rb = orr; }
      }
      if (quad == 0) atomicMax(best + gcol, pack_max(v, rb));
    }
  }
}

// ---------------- distance to NN + -log ----------------
__global__ __launch_bounds__(256) void k_dist(const float* __restrict__ x,
                                              const unsigned long long* __restrict__ best,
                                              float* __restrict__ rowlog) {
  const int row = blockIdx.x;
  const int nb  = (int)(best[row] & 0xffffffffu);
  const int tid = threadIdx.x;
  const float4 a = ((const float4*)(x + (size_t)row * KD))[tid];
  const float4 b = ((const float4*)(x + (size_t)nb * KD))[tid];
  const float dx = a.x - b.x + 1e-6f;   // torch PairwiseDistance eps on the diff
  const float dy = a.y - b.y + 1e-6f;
  const float dz = a.z - b.z + 1e-6f;
  const float dw = a.w - b.w + 1e-6f;
  float ss = dx * dx + dy * dy + dz * dz + dw * dw;
#pragma unroll
  for (int off = 32; off > 0; off >>= 1) ss += __shfl_down(ss, off);
  __shared__ float ws[4];
  if ((tid & 63) == 0) ws[tid >> 6] = ss;
  __syncthreads();
  if (tid == 0) {
    const float total = ws[0] + ws[1] + ws[2] + ws[3];
    rowlog[row] = -logf(sqrtf(total));
  }
}

// ---------------- final mean (1024 threads, 16 waves) ----------------
__global__ __launch_bounds__(1024) void k_final(const float* __restrict__ rowlog,
                                                float* __restrict__ out) {
  const int tid = threadIdx.x;
  float s = 0.f;
  for (int i = tid; i < KN; i += 1024) s += rowlog[i];
#pragma unroll
  for (int off = 32; off > 0; off >>= 1) s += __shfl_down(s, off);
  __shared__ float ws[16];
  if ((tid & 63) == 0) ws[tid >> 6] = s;
  __syncthreads();
  if (tid == 0) {
    float t = 0.f;
#pragma unroll
    for (int i = 0; i < 16; i++) t += ws[i];
    out[0] = t / (float)KN;
  }
}

extern "C" void kernel_launch(void* const* d_in, const int* in_sizes, int n_in,
                              void* d_out, int out_size, void* d_ws, size_t ws_size,
                              hipStream_t stream) {
  const float* x = (const float*)d_in[0];
  float* out = (float*)d_out;

  char* ws = (char*)d_ws;
  __hip_bfloat16* xn = (__hip_bfloat16*)ws;                                   // 32 MB
  unsigned long long* best = (unsigned long long*)(ws + (size_t)KN * KD * 2); // 128 KB
  float* rowlog = (float*)(ws + (size_t)KN * KD * 2 + (size_t)KN * 8);        // 64 KB

  k_normalize<<<KN, 256, 0, stream>>>(x, xn, best);
  dim3 grid(NB / 2 + 1, NB);            // circulant upper-triangle cover
  k_nn_argmax<<<grid, 256, 0, stream>>>(xn, best);
  k_dist<<<KN, 256, 0, stream>>>(x, best, rowlog);
  k_final<<<1, 1024, 0, stream>>>(rowlog, out);
}